// Round 18
// baseline (940.757 us; speedup 1.0000x reference)
//
#include <hip/hip_runtime.h>
#include <math.h>

#define kN 30000
#define kE 240000
#define kG 64
#define kHSZ (1 << 19)
#define kNW 938            // ceil(30000/32)
#define kGrd 938           // sort grid: 938*256 = 240128 >= kE
#define kNP (kGrd * 256)   // padded element count
#define NPG 4              // sort-blocks per scanA thread: 256*4 >= 938
#define CHK 4096           // matcher chunk
#define kMTt 1024          // matcher threads
#define EPT 4              // edges per thread (kMTt*EPT == CHK)

typedef unsigned long long ull;

__device__ __forceinline__ unsigned enc_f(float x) {
  unsigned u = __float_as_uint(x);
  return (u & 0x80000000u) ? ~u : (u | 0x80000000u);
}
__device__ __forceinline__ float dec_f(unsigned u) {
  u = (u & 0x80000000u) ? (u ^ 0x80000000u) : ~u;
  return __uint_as_float(u);
}

// ---------------- embed: z = x @ W_embed ----------------
__global__ __launch_bounds__(256) void k_embed(const float* __restrict__ x,
                                               const float* __restrict__ W,
                                               float* __restrict__ z) {
  __shared__ float sW[128 * 64];
  int tid = threadIdx.x;
  for (int i = tid; i < 128 * 64; i += 256) sW[i] = W[i];
  __syncthreads();
  int lane = tid & 63, sub = tid >> 6;
  int row0 = blockIdx.x * 16;
  for (int r = sub; r < 16; r += 4) {
    int n = row0 + r;
    if (n >= kN) continue;
    const float* xr = x + (size_t)n * 128;
    float acc = 0.f;
#pragma unroll
    for (int k = 0; k < 128; ++k) acc = fmaf(xr[k], sW[k * 64 + lane], acc);
    z[(size_t)n * 64 + lane] = acc;
  }
}

// ---------------- per-layer init (also zeroes fused-hist buffers h1,h2) -----
__global__ void k_init(int* __restrict__ cluster, int* __restrict__ partner,
                       float* __restrict__ mult, double* __restrict__ den,
                       int* __restrict__ cnt, int* __restrict__ hkey,
                       int* __restrict__ hmin, float* __restrict__ embs,
                       unsigned* __restrict__ h12, int layer1) {
  int S = gridDim.x * blockDim.x;
  int lim = layer1 ? kHSZ : (2 * kGrd * 256);  // covers h12 both layers
  for (int i = blockIdx.x * blockDim.x + threadIdx.x; i < lim; i += S) {
    if (i < kN) {
      cluster[i] = i;
      partner[i] = -1;
      mult[i] = 1.f;
      den[i] = 0.0;
    }
    if (i < 2 * kGrd * 256) h12[i] = 0u;
    if (i < 8) cnt[i] = 0;
    if (layer1) {
      hkey[i] = -1;
      hmin[i] = 0x7fffffff;
      if (i < 3 * kG * 64) embs[i] = 0.f;
    }
  }
}

// ---------------- per-node half-dots ----------------
__global__ __launch_bounds__(1024) void k_ab(const float* __restrict__ z,
                                             const float* __restrict__ We,
                                             int layer, float* __restrict__ a,
                                             float* __restrict__ b) {
  int wid = (blockIdx.x * 1024 + threadIdx.x) >> 6;
  int lane = threadIdx.x & 63;
  int nw = (gridDim.x * 1024) >> 6;
  float wlo = We[layer * 128 + lane];
  float whi = We[layer * 128 + 64 + lane];
  for (int n = wid; n < kN; n += nw) {
    float zv = z[(size_t)n * 64 + lane];
    float fa = zv * wlo, fb = zv * whi;
#pragma unroll
    for (int m = 32; m > 0; m >>= 1) {
      fa += __shfl_xor(fa, m, 64);
      fb += __shfl_xor(fb, m, 64);
    }
    if (lane == 0) {
      a[n] = fa;
      b[n] = fb;
    }
  }
}

// ---------------- raw edge score + f64 denominator (no-max softmax) ----------
__global__ void k_rawe(const float* __restrict__ a, const float* __restrict__ b,
                       const float* __restrict__ be, int layer,
                       const int* __restrict__ esrc, const int* __restrict__ edst,
                       const int* __restrict__ emask, float* __restrict__ raws,
                       double* __restrict__ den) {
  int e = blockIdx.x * 256 + threadIdx.x;
  if (e >= kE) return;
  if (emask && !emask[e]) return;
  int t = edst[e];
  float raw = a[esrc[e]] + b[t] + be[layer];
  raws[e] = raw;
  atomicAdd(&den[t], exp((double)raw));  // |raw| << 709: no overflow
}

// ---------------- build sortable records + fused pass-1 histogram -----------
// rec = (~enc(score) << 32) | (s | t<<16). ep in (0.5, 1.5] strictly ->
// enc in [0xBF000001, 0xBFC00000]: top byte of ~enc constant (pass over bits
// 56..63 is identity -> skipped), and ~enc low-3-bytes <= 0xFFFFFE so pads
// (~0ULL) sort strictly last. Stable LSD keeps edge-id tie order.
__global__ __launch_bounds__(256) void k_score(
    const float* __restrict__ raws, const double* __restrict__ den,
    const int* __restrict__ esrc, const int* __restrict__ edst,
    const int* __restrict__ emask, ull* __restrict__ recs, int* __restrict__ cnt,
    unsigned* __restrict__ hist) {
  __shared__ unsigned h[256];
  int tid = threadIdx.x;
  h[tid] = 0;
  __syncthreads();
  int e = blockIdx.x * 256 + tid;
  ull rec = ~0ULL;
  bool live = false;
  if (e < kE && (!emask || emask[e])) {
    int s = esrc[e], t = edst[e];
    double ex = exp((double)raws[e]);
    float ep = (float)(ex / den[t]) + 0.5f;
    unsigned enc = enc_f(ep);
    if (enc == 0xBF000000u) enc = 0xBF000001u;  // unreachable guard (ep>0.5)
    rec = ((ull)(~enc) << 32) | (unsigned)(s | (t << 16));
    live = true;
  }
  recs[e] = rec;
  atomicAdd(&h[(unsigned)(rec >> 32) & 255u], 1u);
  ull mb = __ballot(live);
  if ((tid & 63) == 0 && mb) atomicAdd(cnt, (int)__popcll(mb));
  __syncthreads();
  hist[blockIdx.x * 256 + tid] = h[tid];
}

// ---------------- parallel scan A: one block per digit ----------------
// Thread th owns sort-blocks g in [th*NPG, th*NPG+NPG); computes in-place
// exclusive prefix of hist column d over g (order preserved); digitTot[d]
// gets the column total.
__global__ __launch_bounds__(256) void k_scanA(unsigned* __restrict__ hist,
                                               unsigned* __restrict__ digitTot) {
  __shared__ unsigned sd[256];
  const int d = blockIdx.x;
  const int th = threadIdx.x;
  unsigned v[NPG];
  unsigned s = 0;
#pragma unroll
  for (int j = 0; j < NPG; ++j) {
    int g = th * NPG + j;
    v[j] = (g < kGrd) ? hist[g * 256 + d] : 0u;
    s += v[j];
  }
  sd[th] = s;
  __syncthreads();
  unsigned x = s;  // inclusive Hillis-Steele
  for (int o = 1; o < 256; o <<= 1) {
    unsigned t = (th >= o) ? sd[th - o] : 0u;
    __syncthreads();
    x += t;
    sd[th] = x;
    __syncthreads();
  }
  unsigned run = x - s;  // exclusive prefix for this thread's first block
#pragma unroll
  for (int j = 0; j < NPG; ++j) {
    int g = th * NPG + j;
    if (g < kGrd) {
      unsigned tmp = v[j];
      hist[g * 256 + d] = run;
      run += tmp;
    }
  }
  if (th == 255) digitTot[d] = x;
}

// ---------------- radix sort pass: stable scatter ----------------
// digitBase computed in-prologue from digitTot (r17-proven). NEW (r18): the
// NEXT pass's histogram is accumulated inline via global atomics at
// nhist[(dest>>8)*256 + next_digit] -- exactly what k_hist computed from the
// output array (block g = output elements [g*256,(g+1)*256)), each element
// written exactly once. nhist must be pre-zeroed (k_init).
__global__ __launch_bounds__(256) void k_scatter(
    const ull* __restrict__ in, ull* __restrict__ out,
    const unsigned* __restrict__ hist, const unsigned* __restrict__ digitTot,
    int shift, unsigned* __restrict__ nhist, int nshift) {
  __shared__ unsigned whist[4][256];
  __shared__ unsigned sbase[256];
  int tid = threadIdx.x, w = tid >> 6, lane = tid & 63;
  for (int k = tid; k < 1024; k += 256) ((unsigned*)whist)[k] = 0;
  // exclusive scan of digitTot -> sbase
  unsigned sv = digitTot[tid];
  sbase[tid] = sv;
  __syncthreads();
  unsigned xv = sv;
  for (int o = 1; o < 256; o <<= 1) {
    unsigned t2 = (tid >= o) ? sbase[tid - o] : 0u;
    __syncthreads();
    xv += t2;
    sbase[tid] = xv;
    __syncthreads();
  }
  sbase[tid] = xv - sv;
  __syncthreads();
  ull rec = in[blockIdx.x * 256 + tid];
  unsigned d = (unsigned)(rec >> shift) & 255u;
  ull m = ~0ULL;
#pragma unroll
  for (int b = 0; b < 8; ++b) {
    ull bb = __ballot((d >> b) & 1u);
    m &= ((d >> b) & 1u) ? bb : ~bb;
  }
  int rank = __popcll(m & ((1ULL << lane) - 1ULL));
  int leader = __ffsll(m) - 1;
  if (lane == leader) whist[w][d] = (unsigned)__popcll(m);
  __syncthreads();
  unsigned wp = 0;
  for (int w2 = 0; w2 < w; ++w2) wp += whist[w2][d];
  unsigned dest = sbase[d] + hist[blockIdx.x * 256 + d] + wp + (unsigned)rank;
  out[dest] = rec;
  if (nhist) {
    unsigned d2 = (unsigned)(rec >> nshift) & 255u;
    atomicAdd(&nhist[(dest >> 8) * 256 + d2], 1u);
  }
}

// ---------------- exact sequential-greedy matcher (single WG, LDS) ----------
// Sorted chunks of 4096 (1024 thr x 4). Epoch-tagged claims via atomicMax:
// pk = (epoch<<13)|(4095-pos); stale epochs dominated automatically. Winner
// holds its own pk at both endpoints = min chunk position among undecided
// -> exact sequential greedy. Parity-flag exit (r10/r13/r14/r16/r17-proven).
// Next chunk prefetched during iterations.
__global__ __launch_bounds__(kMTt) void k_matchS(const ull* __restrict__ recs,
                                                 const int* __restrict__ cnt,
                                                 int* __restrict__ cluster,
                                                 int* __restrict__ partner,
                                                 float* __restrict__ mult) {
  extern __shared__ unsigned lds[];
  unsigned* claim = lds;       // [kN], init 0; pk always > 0
  unsigned* avail = lds + kN;  // [kNW]
  __shared__ int sh_any[2];
  const int tid = threadIdx.x;
  for (int i = tid; i < kN; i += kMTt) claim[i] = 0u;
  for (int w = tid; w < kNW; w += kMTt) {
    int rem = kN - (w << 5);
    avail[w] = (rem >= 32) ? ~0u : ((1u << rem) - 1u);
  }
  if (tid == 0) { sh_any[0] = 0; sh_any[1] = 0; }
  __syncthreads();
  const int nlive = cnt[0];
  const int nch = (nlive + CHK - 1) / CHK;
  unsigned epoch = 1;  // max epochs ~ nch*2000 < 2^18: (epoch<<13) < 2^31 safe
  ull cur[EPT];
#pragma unroll
  for (int k = 0; k < EPT; ++k) {
    int gi = EPT * tid + k;
    cur[k] = (gi < nlive) ? recs[gi] : ~0ULL;
  }
  for (int c = 0; c < nch; ++c) {
    ull nxt[EPT];
    if (c + 1 < nch) {
      int base = (c + 1) * CHK;
#pragma unroll
      for (int k = 0; k < EPT; ++k) {
        int gi = base + EPT * tid + k;
        nxt[k] = (gi < nlive) ? recs[gi] : ~0ULL;
      }
    }
    int s[EPT], t[EPT];
    unsigned en[EPT];
    int done[EPT];
#pragma unroll
    for (int k = 0; k < EPT; ++k) {
      done[k] = 1;
      if (cur[k] != ~0ULL) {
        unsigned lo = (unsigned)cur[k];
        s[k] = lo & 0xFFFF;
        t[k] = (lo >> 16) & 0xFFFF;
        en[k] = ~((unsigned)(cur[k] >> 32));
        done[k] = 0;
      }
    }
    for (int iter = 0; iter < 2000; ++iter, ++epoch) {
      // P: death-check + epoch-tagged claim posts
      unsigned pk[EPT];
      int posted = 0;
#pragma unroll
      for (int k = 0; k < EPT; ++k) {
        pk[k] = 0;
        if (done[k]) continue;
        if (!((avail[s[k] >> 5] >> (s[k] & 31)) & 1u) ||
            !((avail[t[k] >> 5] >> (t[k] & 31)) & 1u)) {
          done[k] = 1;
          continue;
        }
        pk[k] = (epoch << 13) | (unsigned)(4095 - (EPT * tid + k));
        atomicMax(&claim[s[k]], pk[k]);
        atomicMax(&claim[t[k]], pk[k]);
        posted = 1;
      }
      if (posted) sh_any[epoch & 1] = 1;          // benign same-value race
      if (tid == 0) sh_any[(epoch + 1) & 1] = 0;  // pre-zero next parity
      __syncthreads();
      if (!sh_any[epoch & 1]) break;  // uniform: nobody posted this epoch
      // W: winners hold their own pk at both endpoints
#pragma unroll
      for (int k = 0; k < EPT; ++k) {
        if (!pk[k]) continue;
        if (claim[s[k]] == pk[k] && claim[t[k]] == pk[k]) {
          atomicAnd(&avail[s[k] >> 5], ~(1u << (s[k] & 31)));
          atomicAnd(&avail[t[k] >> 5], ~(1u << (t[k] & 31)));
          cluster[t[k]] = s[k];
          partner[s[k]] = t[k];
          mult[s[k]] = dec_f(en[k]);
          done[k] = 1;
        }
      }
      __syncthreads();
    }
#pragma unroll
    for (int k = 0; k < EPT; ++k) cur[k] = nxt[k];
  }
}

// ---------------- fused merged-features + graph pooling ----------------
__global__ __launch_bounds__(256) void k_newx_pool(
    const float* __restrict__ z, const int* __restrict__ cluster,
    const int* __restrict__ partner, const float* __restrict__ mult,
    const int* __restrict__ batch, float* __restrict__ zo,
    float* __restrict__ embs_g) {
  int tid = threadIdx.x;
  int d = tid & 63;
  int n0 = blockIdx.x * 128 + (tid >> 6) * 32;
  float acc = 0.f;
  int curg = -1;
  for (int k = 0; k < 32; ++k) {
    int n = n0 + k;
    if (n >= kN) break;
    int g = batch[n];
    if (g != curg) {
      if (curg >= 0 && acc != 0.f) atomicAdd(&embs_g[curg * 64 + d], acc);
      acc = 0.f;
      curg = g;
    }
    float v;
    if (cluster) {
      v = 0.f;
      if (cluster[n] == n) {
        v = z[(size_t)n * 64 + d];
        int p = partner[n];
        if (p >= 0 && p != n) v += z[(size_t)p * 64 + d];
        v *= mult[n];
      }
    } else {
      v = z[(size_t)n * 64 + d];
    }
    if (zo) zo[(size_t)n * 64 + d] = v;
    acc += v;
  }
  if (curg >= 0 && acc != 0.f) atomicAdd(&embs_g[curg * 64 + d], acc);
}

// ---------------- edge remap + hash-dedup ----------------
__global__ void k_remap(const int* __restrict__ esrc, const int* __restrict__ edst,
                        const int* __restrict__ cluster, const int* __restrict__ emask,
                        int* __restrict__ esrcn, int* __restrict__ edstn,
                        int* __restrict__ hkey, int* __restrict__ hmin,
                        int* __restrict__ hslot) {
  int e = blockIdx.x * 256 + threadIdx.x;
  if (e >= kE) return;
  int ns = cluster[esrc[e]];
  int nt = cluster[edst[e]];
  esrcn[e] = ns;
  edstn[e] = nt;
  if (emask && !emask[e]) return;
  int key = ns * kN + nt;
  unsigned h = (((unsigned)key * 2654435761u) >> 13) & (kHSZ - 1);
  while (true) {
    int old = atomicCAS(&hkey[h], -1, key);
    if (old == -1 || old == key) break;
    h = (h + 1) & (kHSZ - 1);
  }
  atomicMin(&hmin[h], e);
  hslot[e] = (int)h;
}

__global__ void k_dedup(const int* __restrict__ emask, const int* __restrict__ hmin,
                        const int* __restrict__ hslot, int* __restrict__ emaskn) {
  int e = blockIdx.x * 256 + threadIdx.x;
  if (e >= kE) return;
  int keep = 0;
  if (!emask || emask[e]) keep = (hmin[hslot[e]] == e) ? 1 : 0;
  emaskn[e] = keep;
}

// ---------------- final FC ----------------
__global__ void k_final(const float* __restrict__ embs, const float* __restrict__ Wfc,
                        const float* __restrict__ bfc, float* __restrict__ out) {
  int tid = threadIdx.x;
  if (tid >= kG * 10) return;
  int g = tid / 10, c = tid % 10;
  float acc = bfc[c];
  for (int l = 0; l < 3; ++l)
    for (int d = 0; d < 64; ++d)
      acc += embs[l * (kG * 64) + g * 64 + d] * Wfc[(l * 64 + d) * 10 + c];
  out[g * 10 + c] = acc;
}

extern "C" void kernel_launch(void* const* d_in, const int* in_sizes, int n_in,
                              void* d_out, int out_size, void* d_ws, size_t ws_size,
                              hipStream_t stream) {
  (void)in_sizes; (void)n_in; (void)out_size; (void)ws_size;
  const float* x = (const float*)d_in[0];
  const int* ei = (const int*)d_in[1];  // [2,E]: src = ei, dst = ei + kE
  const int* batch = (const int*)d_in[2];
  const float* Wemb = (const float*)d_in[3];
  const float* We = (const float*)d_in[4];
  const float* be = (const float*)d_in[5];
  const float* Wfc = (const float*)d_in[6];
  const float* bfc = (const float*)d_in[7];
  float* out = (float*)d_out;

  char* ws = (char*)d_ws;
  size_t off = 0;
  auto alloc = [&](size_t bytes) -> void* {
    void* p = ws + off;
    off = (off + bytes + 255) & ~(size_t)255;
    return p;
  };
  float* z0 = (float*)alloc((size_t)kN * 64 * 4);
  float* z1 = (float*)alloc((size_t)kN * 64 * 4);
  float* raws = (float*)alloc((size_t)kE * 4);
  float* an = (float*)alloc((size_t)kN * 4);
  float* bn = (float*)alloc((size_t)kN * 4);
  double* den = (double*)alloc((size_t)kN * 8);
  ull* recsA = (ull*)alloc((size_t)kNP * 8);
  ull* recsB = (ull*)alloc((size_t)kNP * 8);
  unsigned* h0 = (unsigned*)alloc((size_t)kGrd * 256 * 4);
  unsigned* h12 = (unsigned*)alloc((size_t)2 * kGrd * 256 * 4);  // h1 | h2
  unsigned* h1 = h12;
  unsigned* h2 = h12 + (size_t)kGrd * 256;
  unsigned* digitTot = (unsigned*)alloc(256 * 4);
  int* cluster = (int*)alloc((size_t)kN * 4);
  int* partner = (int*)alloc((size_t)kN * 4);
  float* mult = (float*)alloc((size_t)kN * 4);
  int* esrc1 = (int*)alloc((size_t)kE * 4);
  int* edst1 = (int*)alloc((size_t)kE * 4);
  int* emask1 = (int*)alloc((size_t)kE * 4);
  int* hkey = (int*)alloc((size_t)kHSZ * 4);
  int* hmin = (int*)alloc((size_t)kHSZ * 4);
  int* hslot = (int*)alloc((size_t)kE * 4);
  float* embs = (float*)alloc((size_t)3 * kG * 64 * 4);
  int* cnt = (int*)alloc(256);

  const int gE = (kE + 255) / 256;   // 938
  const int gNP = (kN + 127) / 128;  // 235
  const unsigned ldsBytes = (kN + kNW) * 4;  // ~124 KB dynamic LDS

  // ---------------- layer 1 ----------------
  k_init<<<512, 256, 0, stream>>>(cluster, partner, mult, den, cnt, hkey, hmin,
                                  embs, h12, 1);
  k_embed<<<kN / 16, 256, 0, stream>>>(x, Wemb, z0);
  k_newx_pool<<<gNP, 256, 0, stream>>>(z0, nullptr, nullptr, nullptr, batch, nullptr,
                                       embs);  // embs[0]
  k_ab<<<480, 1024, 0, stream>>>(z0, We, 0, an, bn);
  k_rawe<<<gE, 256, 0, stream>>>(an, bn, be, 0, ei, ei + kE, nullptr, raws, den);
  k_score<<<kGrd, 256, 0, stream>>>(raws, den, ei, ei + kE, nullptr, recsA, cnt, h0);
  // stable LSD radix over score bytes 32..55; next-pass hist fused in scatter
  k_scanA<<<256, 256, 0, stream>>>(h0, digitTot);
  k_scatter<<<kGrd, 256, 0, stream>>>(recsA, recsB, h0, digitTot, 32, h1, 40);
  k_scanA<<<256, 256, 0, stream>>>(h1, digitTot);
  k_scatter<<<kGrd, 256, 0, stream>>>(recsB, recsA, h1, digitTot, 40, h2, 48);
  k_scanA<<<256, 256, 0, stream>>>(h2, digitTot);
  k_scatter<<<kGrd, 256, 0, stream>>>(recsA, recsB, h2, digitTot, 48, nullptr, 0);
  k_matchS<<<1, kMTt, ldsBytes, stream>>>(recsB, cnt, cluster, partner, mult);
  k_newx_pool<<<gNP, 256, 0, stream>>>(z0, cluster, partner, mult, batch, z1,
                                       embs + kG * 64);  // z1 + embs[1]
  k_remap<<<gE, 256, 0, stream>>>(ei, ei + kE, cluster, nullptr, esrc1, edst1, hkey,
                                  hmin, hslot);
  k_dedup<<<gE, 256, 0, stream>>>(nullptr, hmin, hslot, emask1);

  // ---------------- layer 2 ----------------
  k_init<<<512, 256, 0, stream>>>(cluster, partner, mult, den, cnt, hkey, hmin,
                                  embs, h12, 0);
  k_ab<<<480, 1024, 0, stream>>>(z1, We, 1, an, bn);
  k_rawe<<<gE, 256, 0, stream>>>(an, bn, be, 1, esrc1, edst1, emask1, raws, den);
  k_score<<<kGrd, 256, 0, stream>>>(raws, den, esrc1, edst1, emask1, recsA, cnt, h0);
  k_scanA<<<256, 256, 0, stream>>>(h0, digitTot);
  k_scatter<<<kGrd, 256, 0, stream>>>(recsA, recsB, h0, digitTot, 32, h1, 40);
  k_scanA<<<256, 256, 0, stream>>>(h1, digitTot);
  k_scatter<<<kGrd, 256, 0, stream>>>(recsB, recsA, h1, digitTot, 40, h2, 48);
  k_scanA<<<256, 256, 0, stream>>>(h2, digitTot);
  k_scatter<<<kGrd, 256, 0, stream>>>(recsA, recsB, h2, digitTot, 48, nullptr, 0);
  k_matchS<<<1, kMTt, ldsBytes, stream>>>(recsB, cnt, cluster, partner, mult);
  k_newx_pool<<<gNP, 256, 0, stream>>>(z1, cluster, partner, mult, batch, nullptr,
                                       embs + 2 * kG * 64);  // embs[2]

  k_final<<<1, 640, 0, stream>>>(embs, Wfc, bfc, out);
}

// Round 19
// 905.323 us; speedup vs baseline: 1.0391x; 1.0391x over previous
//
#include <hip/hip_runtime.h>
#include <math.h>

#define kN 30000
#define kE 240000
#define kG 64
#define kHSZ (1 << 19)
#define kNW 938            // ceil(30000/32)
#define kGrd 938           // sort grid: 938*256 = 240128 >= kE
#define kNP (kGrd * 256)   // padded element count
#define NPG 4              // sort-blocks per scanA thread: 256*4 >= 938
#define CHK 4096           // matcher chunk
#define kMTt 1024          // matcher threads
#define EPT 4              // edges per thread (kMTt*EPT == CHK)

typedef unsigned long long ull;

__device__ __forceinline__ unsigned enc_f(float x) {
  unsigned u = __float_as_uint(x);
  return (u & 0x80000000u) ? ~u : (u | 0x80000000u);
}
__device__ __forceinline__ float dec_f(unsigned u) {
  u = (u & 0x80000000u) ? (u ^ 0x80000000u) : ~u;
  return __uint_as_float(u);
}

// ---------------- embed: z = x @ W_embed ----------------
__global__ __launch_bounds__(256) void k_embed(const float* __restrict__ x,
                                               const float* __restrict__ W,
                                               float* __restrict__ z) {
  __shared__ float sW[128 * 64];
  int tid = threadIdx.x;
  for (int i = tid; i < 128 * 64; i += 256) sW[i] = W[i];
  __syncthreads();
  int lane = tid & 63, sub = tid >> 6;
  int row0 = blockIdx.x * 16;
  for (int r = sub; r < 16; r += 4) {
    int n = row0 + r;
    if (n >= kN) continue;
    const float* xr = x + (size_t)n * 128;
    float acc = 0.f;
#pragma unroll
    for (int k = 0; k < 128; ++k) acc = fmaf(xr[k], sW[k * 64 + lane], acc);
    z[(size_t)n * 64 + lane] = acc;
  }
}

// ---------------- per-layer init ----------------
__global__ void k_init(int* __restrict__ cluster, int* __restrict__ partner,
                       float* __restrict__ mult, double* __restrict__ den,
                       int* __restrict__ cnt, int* __restrict__ hkey,
                       int* __restrict__ hmin, float* __restrict__ embs,
                       int layer1) {
  int S = gridDim.x * blockDim.x;
  int lim = layer1 ? kHSZ : kN;  // hash table + embs only need init once
  for (int i = blockIdx.x * blockDim.x + threadIdx.x; i < lim; i += S) {
    if (i < kN) {
      cluster[i] = i;
      partner[i] = -1;
      mult[i] = 1.f;
      den[i] = 0.0;
    }
    if (i < 8) cnt[i] = 0;
    if (layer1) {
      hkey[i] = -1;
      hmin[i] = 0x7fffffff;
      if (i < 3 * kG * 64) embs[i] = 0.f;
    }
  }
}

// ---------------- per-node half-dots ----------------
__global__ __launch_bounds__(1024) void k_ab(const float* __restrict__ z,
                                             const float* __restrict__ We,
                                             int layer, float* __restrict__ a,
                                             float* __restrict__ b) {
  int wid = (blockIdx.x * 1024 + threadIdx.x) >> 6;
  int lane = threadIdx.x & 63;
  int nw = (gridDim.x * 1024) >> 6;
  float wlo = We[layer * 128 + lane];
  float whi = We[layer * 128 + 64 + lane];
  for (int n = wid; n < kN; n += nw) {
    float zv = z[(size_t)n * 64 + lane];
    float fa = zv * wlo, fb = zv * whi;
#pragma unroll
    for (int m = 32; m > 0; m >>= 1) {
      fa += __shfl_xor(fa, m, 64);
      fb += __shfl_xor(fb, m, 64);
    }
    if (lane == 0) {
      a[n] = fa;
      b[n] = fb;
    }
  }
}

// ---------------- raw edge score + f64 denominator (no-max softmax) ----------
__global__ void k_rawe(const float* __restrict__ a, const float* __restrict__ b,
                       const float* __restrict__ be, int layer,
                       const int* __restrict__ esrc, const int* __restrict__ edst,
                       const int* __restrict__ emask, float* __restrict__ raws,
                       double* __restrict__ den) {
  int e = blockIdx.x * 256 + threadIdx.x;
  if (e >= kE) return;
  if (emask && !emask[e]) return;
  int t = edst[e];
  float raw = a[esrc[e]] + b[t] + be[layer];
  raws[e] = raw;
  atomicAdd(&den[t], exp((double)raw));  // |raw| << 709: no overflow
}

// ---------------- build sortable records + fused pass-1 histogram -----------
// rec = (~enc(score) << 32) | (s | t<<16). ep in (0.5, 1.5] strictly ->
// enc in [0xBF000001, 0xBFC00000]: top byte of ~enc constant (pass over bits
// 56..63 is identity -> skipped), and ~enc low-3-bytes <= 0xFFFFFE so pads
// (~0ULL) sort strictly last. Stable LSD keeps edge-id tie order.
__global__ __launch_bounds__(256) void k_score(
    const float* __restrict__ raws, const double* __restrict__ den,
    const int* __restrict__ esrc, const int* __restrict__ edst,
    const int* __restrict__ emask, ull* __restrict__ recs, int* __restrict__ cnt,
    unsigned* __restrict__ hist) {
  __shared__ unsigned h[256];
  int tid = threadIdx.x;
  h[tid] = 0;
  __syncthreads();
  int e = blockIdx.x * 256 + tid;
  ull rec = ~0ULL;
  bool live = false;
  if (e < kE && (!emask || emask[e])) {
    int s = esrc[e], t = edst[e];
    double ex = exp((double)raws[e]);
    float ep = (float)(ex / den[t]) + 0.5f;
    unsigned enc = enc_f(ep);
    if (enc == 0xBF000000u) enc = 0xBF000001u;  // unreachable guard (ep>0.5)
    rec = ((ull)(~enc) << 32) | (unsigned)(s | (t << 16));
    live = true;
  }
  recs[e] = rec;
  atomicAdd(&h[(unsigned)(rec >> 32) & 255u], 1u);
  ull mb = __ballot(live);
  if ((tid & 63) == 0 && mb) atomicAdd(cnt, (int)__popcll(mb));
  __syncthreads();
  hist[blockIdx.x * 256 + tid] = h[tid];
}

// ---------------- radix sort pass: histogram ----------------
__global__ __launch_bounds__(256) void k_hist(const ull* __restrict__ in,
                                              unsigned* __restrict__ hist,
                                              int shift) {
  __shared__ unsigned h[256];
  int tid = threadIdx.x;
  h[tid] = 0;
  __syncthreads();
  unsigned d = (unsigned)(in[blockIdx.x * 256 + tid] >> shift) & 255u;
  atomicAdd(&h[d], 1u);
  __syncthreads();
  hist[blockIdx.x * 256 + tid] = h[tid];
}

// ---------------- parallel scan A: one block per digit ----------------
// Thread th owns sort-blocks g in [th*NPG, th*NPG+NPG); computes in-place
// exclusive prefix of hist column d over g (order preserved); digitTot[d]
// gets the column total.
__global__ __launch_bounds__(256) void k_scanA(unsigned* __restrict__ hist,
                                               unsigned* __restrict__ digitTot) {
  __shared__ unsigned sd[256];
  const int d = blockIdx.x;
  const int th = threadIdx.x;
  unsigned v[NPG];
  unsigned s = 0;
#pragma unroll
  for (int j = 0; j < NPG; ++j) {
    int g = th * NPG + j;
    v[j] = (g < kGrd) ? hist[g * 256 + d] : 0u;
    s += v[j];
  }
  sd[th] = s;
  __syncthreads();
  unsigned x = s;  // inclusive Hillis-Steele
  for (int o = 1; o < 256; o <<= 1) {
    unsigned t = (th >= o) ? sd[th - o] : 0u;
    __syncthreads();
    x += t;
    sd[th] = x;
    __syncthreads();
  }
  unsigned run = x - s;  // exclusive prefix for this thread's first block
#pragma unroll
  for (int j = 0; j < NPG; ++j) {
    int g = th * NPG + j;
    if (g < kGrd) {
      unsigned tmp = v[j];
      hist[g * 256 + d] = run;
      run += tmp;
    }
  }
  if (th == 255) digitTot[d] = x;
}

// ---------------- radix sort pass: stable scatter (digitBase computed
// in-prologue from digitTot: 256-wide exclusive scan in LDS) ----------------
__global__ __launch_bounds__(256) void k_scatter(
    const ull* __restrict__ in, ull* __restrict__ out,
    const unsigned* __restrict__ hist, const unsigned* __restrict__ digitTot,
    int shift) {
  __shared__ unsigned whist[4][256];
  __shared__ unsigned sbase[256];
  int tid = threadIdx.x, w = tid >> 6, lane = tid & 63;
  for (int k = tid; k < 1024; k += 256) ((unsigned*)whist)[k] = 0;
  // exclusive scan of digitTot -> sbase
  unsigned sv = digitTot[tid];
  sbase[tid] = sv;
  __syncthreads();
  unsigned xv = sv;
  for (int o = 1; o < 256; o <<= 1) {
    unsigned t2 = (tid >= o) ? sbase[tid - o] : 0u;
    __syncthreads();
    xv += t2;
    sbase[tid] = xv;
    __syncthreads();
  }
  sbase[tid] = xv - sv;
  __syncthreads();
  ull rec = in[blockIdx.x * 256 + tid];
  unsigned d = (unsigned)(rec >> shift) & 255u;
  ull m = ~0ULL;
#pragma unroll
  for (int b = 0; b < 8; ++b) {
    ull bb = __ballot((d >> b) & 1u);
    m &= ((d >> b) & 1u) ? bb : ~bb;
  }
  int rank = __popcll(m & ((1ULL << lane) - 1ULL));
  int leader = __ffsll(m) - 1;
  if (lane == leader) whist[w][d] = (unsigned)__popcll(m);
  __syncthreads();
  unsigned wp = 0;
  for (int w2 = 0; w2 < w; ++w2) wp += whist[w2][d];
  unsigned dest = sbase[d] + hist[blockIdx.x * 256 + d] + wp + (unsigned)rank;
  out[dest] = rec;
}

// ---------------- exact sequential-greedy matcher (single WG, LDS) ----------
// Sorted chunks of 4096 (1024 thr x 4). Epoch-tagged claims via atomicMax:
// pk = (epoch<<13)|(4095-pos); stale epochs dominated automatically. Winner
// holds its own pk at both endpoints = min chunk position among undecided
// -> exact sequential greedy. Parity-flag exit (r10/r13/r14/r16/r17-proven).
// Next chunk prefetched during iterations.
__global__ __launch_bounds__(kMTt) void k_matchS(const ull* __restrict__ recs,
                                                 const int* __restrict__ cnt,
                                                 int* __restrict__ cluster,
                                                 int* __restrict__ partner,
                                                 float* __restrict__ mult) {
  extern __shared__ unsigned lds[];
  unsigned* claim = lds;       // [kN], init 0; pk always > 0
  unsigned* avail = lds + kN;  // [kNW]
  __shared__ int sh_any[2];
  const int tid = threadIdx.x;
  for (int i = tid; i < kN; i += kMTt) claim[i] = 0u;
  for (int w = tid; w < kNW; w += kMTt) {
    int rem = kN - (w << 5);
    avail[w] = (rem >= 32) ? ~0u : ((1u << rem) - 1u);
  }
  if (tid == 0) { sh_any[0] = 0; sh_any[1] = 0; }
  __syncthreads();
  const int nlive = cnt[0];
  const int nch = (nlive + CHK - 1) / CHK;
  unsigned epoch = 1;  // max epochs ~ nch*2000 < 2^18: (epoch<<13) < 2^31 safe
  ull cur[EPT];
#pragma unroll
  for (int k = 0; k < EPT; ++k) {
    int gi = EPT * tid + k;
    cur[k] = (gi < nlive) ? recs[gi] : ~0ULL;
  }
  for (int c = 0; c < nch; ++c) {
    ull nxt[EPT];
    if (c + 1 < nch) {
      int base = (c + 1) * CHK;
#pragma unroll
      for (int k = 0; k < EPT; ++k) {
        int gi = base + EPT * tid + k;
        nxt[k] = (gi < nlive) ? recs[gi] : ~0ULL;
      }
    }
    int s[EPT], t[EPT];
    unsigned en[EPT];
    int done[EPT];
#pragma unroll
    for (int k = 0; k < EPT; ++k) {
      done[k] = 1;
      if (cur[k] != ~0ULL) {
        unsigned lo = (unsigned)cur[k];
        s[k] = lo & 0xFFFF;
        t[k] = (lo >> 16) & 0xFFFF;
        en[k] = ~((unsigned)(cur[k] >> 32));
        done[k] = 0;
      }
    }
    for (int iter = 0; iter < 2000; ++iter, ++epoch) {
      // P: death-check + epoch-tagged claim posts
      unsigned pk[EPT];
      int posted = 0;
#pragma unroll
      for (int k = 0; k < EPT; ++k) {
        pk[k] = 0;
        if (done[k]) continue;
        if (!((avail[s[k] >> 5] >> (s[k] & 31)) & 1u) ||
            !((avail[t[k] >> 5] >> (t[k] & 31)) & 1u)) {
          done[k] = 1;
          continue;
        }
        pk[k] = (epoch << 13) | (unsigned)(4095 - (EPT * tid + k));
        atomicMax(&claim[s[k]], pk[k]);
        atomicMax(&claim[t[k]], pk[k]);
        posted = 1;
      }
      if (posted) sh_any[epoch & 1] = 1;          // benign same-value race
      if (tid == 0) sh_any[(epoch + 1) & 1] = 0;  // pre-zero next parity
      __syncthreads();
      if (!sh_any[epoch & 1]) break;  // uniform: nobody posted this epoch
      // W: winners hold their own pk at both endpoints
#pragma unroll
      for (int k = 0; k < EPT; ++k) {
        if (!pk[k]) continue;
        if (claim[s[k]] == pk[k] && claim[t[k]] == pk[k]) {
          atomicAnd(&avail[s[k] >> 5], ~(1u << (s[k] & 31)));
          atomicAnd(&avail[t[k] >> 5], ~(1u << (t[k] & 31)));
          cluster[t[k]] = s[k];
          partner[s[k]] = t[k];
          mult[s[k]] = dec_f(en[k]);
          done[k] = 1;
        }
      }
      __syncthreads();
    }
#pragma unroll
    for (int k = 0; k < EPT; ++k) cur[k] = nxt[k];
  }
}

// ---------------- fused merged-features + graph pooling ----------------
__global__ __launch_bounds__(256) void k_newx_pool(
    const float* __restrict__ z, const int* __restrict__ cluster,
    const int* __restrict__ partner, const float* __restrict__ mult,
    const int* __restrict__ batch, float* __restrict__ zo,
    float* __restrict__ embs_g) {
  int tid = threadIdx.x;
  int d = tid & 63;
  int n0 = blockIdx.x * 128 + (tid >> 6) * 32;
  float acc = 0.f;
  int curg = -1;
  for (int k = 0; k < 32; ++k) {
    int n = n0 + k;
    if (n >= kN) break;
    int g = batch[n];
    if (g != curg) {
      if (curg >= 0 && acc != 0.f) atomicAdd(&embs_g[curg * 64 + d], acc);
      acc = 0.f;
      curg = g;
    }
    float v;
    if (cluster) {
      v = 0.f;
      if (cluster[n] == n) {
        v = z[(size_t)n * 64 + d];
        int p = partner[n];
        if (p >= 0 && p != n) v += z[(size_t)p * 64 + d];
        v *= mult[n];
      }
    } else {
      v = z[(size_t)n * 64 + d];
    }
    if (zo) zo[(size_t)n * 64 + d] = v;
    acc += v;
  }
  if (curg >= 0 && acc != 0.f) atomicAdd(&embs_g[curg * 64 + d], acc);
}

// ---------------- edge remap + hash-dedup ----------------
__global__ void k_remap(const int* __restrict__ esrc, const int* __restrict__ edst,
                        const int* __restrict__ cluster, const int* __restrict__ emask,
                        int* __restrict__ esrcn, int* __restrict__ edstn,
                        int* __restrict__ hkey, int* __restrict__ hmin,
                        int* __restrict__ hslot) {
  int e = blockIdx.x * 256 + threadIdx.x;
  if (e >= kE) return;
  int ns = cluster[esrc[e]];
  int nt = cluster[edst[e]];
  esrcn[e] = ns;
  edstn[e] = nt;
  if (emask && !emask[e]) return;
  int key = ns * kN + nt;
  unsigned h = (((unsigned)key * 2654435761u) >> 13) & (kHSZ - 1);
  while (true) {
    int old = atomicCAS(&hkey[h], -1, key);
    if (old == -1 || old == key) break;
    h = (h + 1) & (kHSZ - 1);
  }
  atomicMin(&hmin[h], e);
  hslot[e] = (int)h;
}

__global__ void k_dedup(const int* __restrict__ emask, const int* __restrict__ hmin,
                        const int* __restrict__ hslot, int* __restrict__ emaskn) {
  int e = blockIdx.x * 256 + threadIdx.x;
  if (e >= kE) return;
  int keep = 0;
  if (!emask || emask[e]) keep = (hmin[hslot[e]] == e) ? 1 : 0;
  emaskn[e] = keep;
}

// ---------------- final FC ----------------
__global__ void k_final(const float* __restrict__ embs, const float* __restrict__ Wfc,
                        const float* __restrict__ bfc, float* __restrict__ out) {
  int tid = threadIdx.x;
  if (tid >= kG * 10) return;
  int g = tid / 10, c = tid % 10;
  float acc = bfc[c];
  for (int l = 0; l < 3; ++l)
    for (int d = 0; d < 64; ++d)
      acc += embs[l * (kG * 64) + g * 64 + d] * Wfc[(l * 64 + d) * 10 + c];
  out[g * 10 + c] = acc;
}

extern "C" void kernel_launch(void* const* d_in, const int* in_sizes, int n_in,
                              void* d_out, int out_size, void* d_ws, size_t ws_size,
                              hipStream_t stream) {
  (void)in_sizes; (void)n_in; (void)out_size; (void)ws_size;
  const float* x = (const float*)d_in[0];
  const int* ei = (const int*)d_in[1];  // [2,E]: src = ei, dst = ei + kE
  const int* batch = (const int*)d_in[2];
  const float* Wemb = (const float*)d_in[3];
  const float* We = (const float*)d_in[4];
  const float* be = (const float*)d_in[5];
  const float* Wfc = (const float*)d_in[6];
  const float* bfc = (const float*)d_in[7];
  float* out = (float*)d_out;

  char* ws = (char*)d_ws;
  size_t off = 0;
  auto alloc = [&](size_t bytes) -> void* {
    void* p = ws + off;
    off = (off + bytes + 255) & ~(size_t)255;
    return p;
  };
  float* z0 = (float*)alloc((size_t)kN * 64 * 4);
  float* z1 = (float*)alloc((size_t)kN * 64 * 4);
  float* raws = (float*)alloc((size_t)kE * 4);
  float* an = (float*)alloc((size_t)kN * 4);
  float* bn = (float*)alloc((size_t)kN * 4);
  double* den = (double*)alloc((size_t)kN * 8);
  ull* recsA = (ull*)alloc((size_t)kNP * 8);
  ull* recsB = (ull*)alloc((size_t)kNP * 8);
  unsigned* hist = (unsigned*)alloc((size_t)kGrd * 256 * 4);
  unsigned* digitTot = (unsigned*)alloc(256 * 4);
  int* cluster = (int*)alloc((size_t)kN * 4);
  int* partner = (int*)alloc((size_t)kN * 4);
  float* mult = (float*)alloc((size_t)kN * 4);
  int* esrc1 = (int*)alloc((size_t)kE * 4);
  int* edst1 = (int*)alloc((size_t)kE * 4);
  int* emask1 = (int*)alloc((size_t)kE * 4);
  int* hkey = (int*)alloc((size_t)kHSZ * 4);
  int* hmin = (int*)alloc((size_t)kHSZ * 4);
  int* hslot = (int*)alloc((size_t)kE * 4);
  float* embs = (float*)alloc((size_t)3 * kG * 64 * 4);
  int* cnt = (int*)alloc(256);

  const int gE = (kE + 255) / 256;   // 938
  const int gNP = (kN + 127) / 128;  // 235
  const unsigned ldsBytes = (kN + kNW) * 4;  // ~124 KB dynamic LDS

  // ---------------- layer 1 ----------------
  k_init<<<512, 256, 0, stream>>>(cluster, partner, mult, den, cnt, hkey, hmin,
                                  embs, 1);
  k_embed<<<kN / 16, 256, 0, stream>>>(x, Wemb, z0);
  k_newx_pool<<<gNP, 256, 0, stream>>>(z0, nullptr, nullptr, nullptr, batch, nullptr,
                                       embs);  // embs[0]
  k_ab<<<480, 1024, 0, stream>>>(z0, We, 0, an, bn);
  k_rawe<<<gE, 256, 0, stream>>>(an, bn, be, 0, ei, ei + kE, nullptr, raws, den);
  k_score<<<kGrd, 256, 0, stream>>>(raws, den, ei, ei + kE, nullptr, recsA, cnt,
                                    hist);
  // stable LSD radix over score bytes 32..55 (top byte provably constant)
  k_scanA<<<256, 256, 0, stream>>>(hist, digitTot);
  k_scatter<<<kGrd, 256, 0, stream>>>(recsA, recsB, hist, digitTot, 32);
  k_hist<<<kGrd, 256, 0, stream>>>(recsB, hist, 40);
  k_scanA<<<256, 256, 0, stream>>>(hist, digitTot);
  k_scatter<<<kGrd, 256, 0, stream>>>(recsB, recsA, hist, digitTot, 40);
  k_hist<<<kGrd, 256, 0, stream>>>(recsA, hist, 48);
  k_scanA<<<256, 256, 0, stream>>>(hist, digitTot);
  k_scatter<<<kGrd, 256, 0, stream>>>(recsA, recsB, hist, digitTot, 48);
  k_matchS<<<1, kMTt, ldsBytes, stream>>>(recsB, cnt, cluster, partner, mult);
  k_newx_pool<<<gNP, 256, 0, stream>>>(z0, cluster, partner, mult, batch, z1,
                                       embs + kG * 64);  // z1 + embs[1]
  k_remap<<<gE, 256, 0, stream>>>(ei, ei + kE, cluster, nullptr, esrc1, edst1, hkey,
                                  hmin, hslot);
  k_dedup<<<gE, 256, 0, stream>>>(nullptr, hmin, hslot, emask1);

  // ---------------- layer 2 ----------------
  k_init<<<512, 256, 0, stream>>>(cluster, partner, mult, den, cnt, hkey, hmin,
                                  embs, 0);
  k_ab<<<480, 1024, 0, stream>>>(z1, We, 1, an, bn);
  k_rawe<<<gE, 256, 0, stream>>>(an, bn, be, 1, esrc1, edst1, emask1, raws, den);
  k_score<<<kGrd, 256, 0, stream>>>(raws, den, esrc1, edst1, emask1, recsA, cnt,
                                    hist);
  k_scanA<<<256, 256, 0, stream>>>(hist, digitTot);
  k_scatter<<<kGrd, 256, 0, stream>>>(recsA, recsB, hist, digitTot, 32);
  k_hist<<<kGrd, 256, 0, stream>>>(recsB, hist, 40);
  k_scanA<<<256, 256, 0, stream>>>(hist, digitTot);
  k_scatter<<<kGrd, 256, 0, stream>>>(recsB, recsA, hist, digitTot, 40);
  k_hist<<<kGrd, 256, 0, stream>>>(recsA, hist, 48);
  k_scanA<<<256, 256, 0, stream>>>(hist, digitTot);
  k_scatter<<<kGrd, 256, 0, stream>>>(recsA, recsB, hist, digitTot, 48);
  k_matchS<<<1, kMTt, ldsBytes, stream>>>(recsB, cnt, cluster, partner, mult);
  k_newx_pool<<<gNP, 256, 0, stream>>>(z1, cluster, partner, mult, batch, nullptr,
                                       embs + 2 * kG * 64);  // embs[2]

  k_final<<<1, 640, 0, stream>>>(embs, Wfc, bfc, out);
}